// Round 2
// 152.127 us; speedup vs baseline: 1.0293x; 1.0293x over previous
//
#include <hip/hip_runtime.h>
#include <math.h>

// Shapes (compile-time)
#define BB 16
#define LL 28
#define RR 64
#define DD 512
#define NROLE 256           // role chunks: (r-pair, 64-wide d range), k=64, 2 r each
#define NEVT  256           // evt chunks: (b, 32-wide d range)

// ---------------------------------------------------------------------------
// Kernel A (fused main):
//  bid <  NROLE: role chunk (rp, d0): r = {2rp, 2rp+1} share one 64-d slice.
//    Phase 1 builds G[2][64 rows][16 b] (8 KB LDS) reusing arg float4 loads
//    (logits for the r-pair read as one float2). ONE barrier.
//    Phase 2: half-block h owns k in [32h, 32h+32) for BOTH r -> no duplicate
//    WRT addresses anywhere in the block (WRT fetched exactly once), 8-deep
//    register float4 pipeline, acc[16 b][4 e] in regs. Halves combine via
//    32 KB LDS; half 0 stores partial [16][512] to part[rid].
//  bid >= NROLE: evt chunk (b, 32-d range) -> evt_part (proven path).
// ---------------------------------------------------------------------------
__global__ void __launch_bounds__(256, 2) kernel_a(
    const float* __restrict__ logits,   // [B,L,R]
    const float* __restrict__ arg,      // [B,L,D]
    const float* __restrict__ WRT,      // [R,D,D]
    const float* __restrict__ WTT,      // [E,D,D]
    const float* __restrict__ evt_emb,  // [B,1,D]
    const int*   __restrict__ evt_type, // [B]
    float* __restrict__ part,           // [NROLE][16][512]
    float* __restrict__ evt_part)       // [NEVT][512]
{
    __shared__ float smem[8192];        // 32 KB (G2 8KB, combine 32KB)
    const int t   = threadIdx.x;
    const int bid = blockIdx.x;

    if (bid < NROLE) {
        // ---------------- role chunk: (r-pair rp, d-range d0) ----------------
        const int rid = bid;
        const int rp  = rid >> 3;
        const int d0  = (rid & 7) * 64;

        const float4* Wp0 = (const float4*)(WRT + ((size_t)(2 * rp)     * DD + d0) * DD);
        const float4* Wp1 = (const float4*)(WRT + ((size_t)(2 * rp + 1) * DD + d0) * DD);

        const int e4    = t & 127;      // float4 e-column
        const int h     = t >> 7;       // k-half (halves own disjoint k rows)
        const int kbase = 32 * h;

        // Prefetch WRT batch 0 (this half's k-rows 0..7 of r0) BEFORE phase 1.
        float4 w[8];
#pragma unroll
        for (int i = 0; i < 8; ++i)
            w[i] = Wp0[(size_t)(kbase + i) * 128 + e4];

        // Phase 1: G2[rr][row][b], row = d-local in [0,64), b in [0,16).
        {
            const int b  = t >> 4;
            const int d4 = t & 15;      // float4 d-group (coalesced arg)
            const float4* ap = (const float4*)(arg) + (size_t)(b * LL) * 128 + (d0 >> 2) + d4;
            const float2* lp = (const float2*)(logits + (size_t)(b * LL) * RR) + rp;
            float4 g0 = {0.f, 0.f, 0.f, 0.f};
            float4 g1 = {0.f, 0.f, 0.f, 0.f};
#pragma unroll 7
            for (int l = 0; l < LL; ++l) {
                const float4 av = ap[(size_t)l * 128];
                const float2 lg = lp[(size_t)l * 32];   // logits[b,l,2rp..2rp+1]
                g0.x = fmaf(lg.x, av.x, g0.x); g0.y = fmaf(lg.x, av.y, g0.y);
                g0.z = fmaf(lg.x, av.z, g0.z); g0.w = fmaf(lg.x, av.w, g0.w);
                g1.x = fmaf(lg.y, av.x, g1.x); g1.y = fmaf(lg.y, av.y, g1.y);
                g1.z = fmaf(lg.y, av.z, g1.z); g1.w = fmaf(lg.y, av.w, g1.w);
            }
            smem[(4 * d4 + 0) * 16 + b] = g0.x;
            smem[(4 * d4 + 1) * 16 + b] = g0.y;
            smem[(4 * d4 + 2) * 16 + b] = g0.z;
            smem[(4 * d4 + 3) * 16 + b] = g0.w;
            smem[1024 + (4 * d4 + 0) * 16 + b] = g1.x;
            smem[1024 + (4 * d4 + 1) * 16 + b] = g1.y;
            smem[1024 + (4 * d4 + 2) * 16 + b] = g1.z;
            smem[1024 + (4 * d4 + 3) * 16 + b] = g1.w;
        }
        __syncthreads();

        // Phase 2: 8 macro-batches (rr = mb>>2, 8 k-rows each), reg dbuf.
        float4 acc[16];
#pragma unroll
        for (int i = 0; i < 16; ++i) acc[i] = make_float4(0.f, 0.f, 0.f, 0.f);

        for (int mb = 0; mb < 8; ++mb) {
            const int mbn = (mb + 1) & 7;            // wraps harmlessly at end
            const float4* Wn = (mbn & 4) ? Wp1 : Wp0;
            const int kn = kbase + (mbn & 3) * 8;
            float4 wn[8];
#pragma unroll
            for (int i = 0; i < 8; ++i)
                wn[i] = Wn[(size_t)(kn + i) * 128 + e4];

            const float* Gr = smem + (mb & 4) * 256; // rr * 1024 floats
            const int k0 = kbase + (mb & 3) * 8;
#pragma unroll
            for (int i = 0; i < 8; ++i) {
                const float* gp = Gr + (k0 + i) * 16;
                const float4 ga = ((const float4*)gp)[0];   // uniform b128 bcast
                const float4 gb = ((const float4*)gp)[1];
                const float4 gc = ((const float4*)gp)[2];
                const float4 gd = ((const float4*)gp)[3];
#define ACC(j, S) \
                acc[j].x = fmaf(S, w[i].x, acc[j].x); \
                acc[j].y = fmaf(S, w[i].y, acc[j].y); \
                acc[j].z = fmaf(S, w[i].z, acc[j].z); \
                acc[j].w = fmaf(S, w[i].w, acc[j].w);
                ACC(0,  ga.x) ACC(1,  ga.y) ACC(2,  ga.z) ACC(3,  ga.w)
                ACC(4,  gb.x) ACC(5,  gb.y) ACC(6,  gb.z) ACC(7,  gb.w)
                ACC(8,  gc.x) ACC(9,  gc.y) ACC(10, gc.z) ACC(11, gc.w)
                ACC(12, gd.x) ACC(13, gd.y) ACC(14, gd.z) ACC(15, gd.w)
#undef ACC
            }
#pragma unroll
            for (int i = 0; i < 8; ++i) w[i] = wn[i];
        }

        // Combine k-halves via LDS (G dead now); half 0 stores the partial.
        __syncthreads();
        float4* cb = (float4*)smem;                  // [16][128] float4 = 32 KB
        if (h == 1) {
#pragma unroll
            for (int i = 0; i < 16; ++i)
                cb[i * 128 + e4] = acc[i];           // lane-contig: no conflicts
        }
        __syncthreads();
        if (h == 0) {
            float4* po = (float4*)part + (size_t)rid * 2048;
#pragma unroll
            for (int i = 0; i < 16; ++i) {
                const float4 v = cb[i * 128 + e4];
                acc[i].x += v.x; acc[i].y += v.y; acc[i].z += v.z; acc[i].w += v.w;
                po[i * 128 + e4] = acc[i];
            }
        }
    } else {
        // ---------------- evt transform ----------------
        const int cid = bid - NROLE;    // [0,256)
        const int b   = cid >> 4;
        const int dc  = cid & 15;
        const int d0  = dc * 32;
        const int ty  = evt_type[b];
        const float* Wt = WTT + (size_t)ty * DD * DD;
        const int e4 = t & 127;
        const int s  = t >> 7;          // 2 d-streams
        float4 a = {0.f, 0.f, 0.f, 0.f};
#pragma unroll
        for (int db = 0; db < 32; db += 16) {
            float  em[8];
            float4 wv[8];
#pragma unroll
            for (int i = 0; i < 8; ++i) {
                const int d = d0 + db + s + 2 * i;
                em[i] = evt_emb[b * DD + d];                       // uniform
                wv[i] = ((const float4*)(Wt + (size_t)d * DD))[e4];
            }
#pragma unroll
            for (int i = 0; i < 8; ++i) {
                a.x = fmaf(em[i], wv[i].x, a.x);
                a.y = fmaf(em[i], wv[i].y, a.y);
                a.z = fmaf(em[i], wv[i].z, a.z);
                a.w = fmaf(em[i], wv[i].w, a.w);
            }
        }
        float4* sm4 = (float4*)smem;
        if (s == 1) sm4[e4] = a;
        __syncthreads();
        if (s == 0) {
            const float4 q4 = sm4[e4];
            a.x += q4.x; a.y += q4.y; a.z += q4.z; a.w += q4.w;
            ((float4*)evt_part)[(size_t)cid * 128 + e4] = a;
        }
    }
}

// ---------------------------------------------------------------------------
// Reduce (plain stores):
//  blocks [0,128): div_acc — block owns 16 f4 outputs; 16 p-groups of 16;
//    LDS combine. (256 partials now.)
//  blocks [128,136): evt_acc — sum 16 d-chunks per (b, e4).
// ---------------------------------------------------------------------------
__global__ void __launch_bounds__(256) kernel_reduce(
    const float* __restrict__ part,     // [NROLE][2048] float4-granular
    const float* __restrict__ evt_part, // [256][128] float4-granular
    float* __restrict__ div_acc,        // [8192]
    float* __restrict__ evt_acc)        // [8192]
{
    const int t = threadIdx.x;
    if (blockIdx.x < 128) {
        __shared__ float4 sred[256];
        const int oo = t & 15;
        const int pg = t >> 4;          // 16 groups x 16 partials
        const int o4 = blockIdx.x * 16 + oo;
        const float4* p4 = (const float4*)part;
        float4 s = {0.f, 0.f, 0.f, 0.f};
#pragma unroll 8
        for (int i = 0; i < 16; ++i) {
            const int p = pg * 16 + i;
            const float4 v = p4[(size_t)p * 2048 + o4];
            s.x += v.x; s.y += v.y; s.z += v.z; s.w += v.w;
        }
        sred[pg * 16 + oo] = s;
        __syncthreads();
        if (t < 16) {
            float4 tot = sred[t];
#pragma unroll
            for (int g = 1; g < 16; ++g) {
                const float4 v = sred[g * 16 + t];
                tot.x += v.x; tot.y += v.y; tot.z += v.z; tot.w += v.w;
            }
            ((float4*)div_acc)[blockIdx.x * 16 + t] = tot;
        }
    } else {
        const int o4 = (blockIdx.x - 128) * 256 + t;   // [0,2048)
        const int b  = o4 >> 7;
        const int el = o4 & 127;
        const float4* e4p = (const float4*)evt_part;
        float4 s = {0.f, 0.f, 0.f, 0.f};
#pragma unroll
        for (int dc = 0; dc < 16; ++dc) {
            const float4 v = e4p[(size_t)(b * 16 + dc) * 128 + el];
            s.x += v.x; s.y += v.y; s.z += v.z; s.w += v.w;
        }
        ((float4*)evt_acc)[o4] = s;
    }
}

// ---------------------------------------------------------------------------
// MLP: graph=(div+evt)/2 ; h=relu(graph@w1+b1) ; out=sigmoid(h@w2+b2)
// ---------------------------------------------------------------------------
__global__ void __launch_bounds__(256) kernel_mlp(
    const float* __restrict__ div_acc,  // [B,D]
    const float* __restrict__ evt_acc,  // [B,D]
    const float* __restrict__ w1,       // [D,64]
    const float* __restrict__ b1,       // [64]
    const float* __restrict__ w2,       // [64,1]
    const float* __restrict__ b2,       // [1]
    float* __restrict__ out)            // [B,1]
{
    __shared__ float hred[256];
    const int b  = blockIdx.x;
    const int t  = threadIdx.x;
    const int j  = t & 63;
    const int dq = t >> 6;
    float hp = 0.f;
#pragma unroll 8
    for (int i = 0; i < 128; ++i) {
        const int d = dq * 128 + i;
        const float g = (div_acc[b * DD + d] + evt_acc[b * DD + d]) * 0.5f;
        hp = fmaf(g, w1[d * 64 + j], hp);
    }
    hred[t] = hp;
    __syncthreads();
    if (t < 64) {
        float h = b1[j] + hred[j] + hred[64 + j] + hred[128 + j] + hred[192 + j];
        h = fmaxf(h, 0.f);
        float v = h * w2[j];
#pragma unroll
        for (int off = 32; off > 0; off >>= 1) v += __shfl_down(v, off, 64);
        if (j == 0) out[b] = 1.f / (1.f + expf(-(v + b2[0])));
    }
}

// ---------------------------------------------------------------------------
extern "C" void kernel_launch(void* const* d_in, const int* in_sizes, int n_in,
                              void* d_out, int out_size, void* d_ws, size_t ws_size,
                              hipStream_t stream) {
    const float* logits   = (const float*)d_in[0];
    const float* evt_emb  = (const float*)d_in[1];
    const float* arg_emb  = (const float*)d_in[2];
    // d_in[3] arg_padding_num cancels algebraically; unused
    const int*   evt_type = (const int*)d_in[4];
    const float* WRT      = (const float*)d_in[5];
    const float* WTT      = (const float*)d_in[6];
    const float* w1       = (const float*)d_in[7];
    const float* b1       = (const float*)d_in[8];
    const float* w2       = (const float*)d_in[9];
    const float* b2       = (const float*)d_in[10];
    float* out = (float*)d_out;

    float* part     = (float*)d_ws;                      // 256*8192 floats = 8.39 MB
    float* evt_part = part + (size_t)NROLE * 8192;       // 256*512 floats = 512 KB
    float* div_acc  = evt_part + (size_t)NEVT * DD;      // 8192 floats
    float* evt_acc  = div_acc + BB * DD;                 // 8192 floats

    hipLaunchKernelGGL(kernel_a, dim3(NROLE + NEVT), dim3(256), 0, stream,
                       logits, arg_emb, WRT, WTT, evt_emb, evt_type, part, evt_part);
    hipLaunchKernelGGL(kernel_reduce, dim3(136), dim3(256), 0, stream,
                       part, evt_part, div_acc, evt_acc);
    hipLaunchKernelGGL(kernel_mlp, dim3(BB), dim3(256), 0, stream,
                       div_acc, evt_acc, w1, b1, w2, b2, out);
}